// Round 1
// baseline (369.471 us; speedup 1.0000x reference)
//
#include <hip/hip_runtime.h>

// Problem constants (from reference)
#define P_TOTAL 16384      // H*W pixels
#define KN      16         // kernels per pixel
#define CK      144        // in_channel * kernel_size
#define BATCH   8
#define IMG     262144     // C*H*W
#define PSTRIDE 12         // LDS row stride in floats (48B, 16B-aligned for b128)

// ---------------- main kernel: workspace-free direct-gather version ----------------
// Theory: the 576 MB d_ws poison fill (~90 us each) is inside the timed region and
// only charged because we touch d_ws. Drop the bf16 transpose table entirely and
// gather f32 straight from x. x is 8.4 MB (L3-resident, largely L2-resident per
// XCD), so the 8-plane gather is served by cache; weights (151 MB streaming) remain
// the dominant HBM traffic.
__global__ __launch_bounds__(256) void abc2d_direct(
    const float* __restrict__ x,      // [8][IMG] f32
    const float* __restrict__ w,      // [P, KN, CK]
    const int*   __restrict__ hidx,   // [P, CK]
    float* __restrict__ out)          // [B, KN, P]
{
    __shared__ float patch[CK * PSTRIDE];   // patch[c][b], f32

    // XCD swizzle: consecutive p on the same XCD -> output lines merge in L2,
    // weight stream stays contiguous per XCD.
    const int bid = blockIdx.x;
    const int p   = (bid & 7) * (P_TOTAL / 8) + (bid >> 3);
    const int t   = threadIdx.x;
    const int k   = t >> 4;
    const int cs  = t & 15;

    // ---- weight prefetch: issue this global stream BEFORE the gather so the
    // two latencies overlap inside the block (phase-1 = max, not sum) ----
    const float* wp = w + (size_t)p * (KN * CK) + (size_t)k * CK;
    float wreg[9];
#pragma unroll
    for (int i = 0; i < 9; ++i) wreg[i] = wp[cs + 16 * i];   // 16-lane 64B runs

    // ---------- gather phase (direct from x, no workspace) ----------
    // One thread per hash index: load id once, issue 8 independent plane
    // gathers (8-deep MLP per thread), pack into two b128 LDS writes.
    // LDS write addr word = t*12 -> 2-way bank alias across the wave = free.
    if (t < CK) {
        const int id = hidx[p * CK + t];
        float v[BATCH];
#pragma unroll
        for (int b = 0; b < BATCH; ++b)
            v[b] = x[(size_t)b * IMG + (size_t)id];
        float* pr = &patch[t * PSTRIDE];
        *reinterpret_cast<float4*>(pr)     = make_float4(v[0], v[1], v[2], v[3]);
        *reinterpret_cast<float4*>(pr + 4) = make_float4(v[4], v[5], v[6], v[7]);
    }
    __syncthreads();

    // ---------- compute phase ----------
    // c = cs + 16*i: LDS word-step 12/lane, gcd(12,32)=4 -> 2-way alias = free
    float acc[BATCH];
#pragma unroll
    for (int b = 0; b < BATCH; ++b) acc[b] = 0.f;

#pragma unroll
    for (int i = 0; i < 9; ++i) {
        const int c = cs + 16 * i;
        const float wv = wreg[i];
        const float* pr = &patch[c * PSTRIDE];
        const float4 p0 = *reinterpret_cast<const float4*>(pr);
        const float4 p1 = *reinterpret_cast<const float4*>(pr + 4);
        acc[0] += wv * p0.x;
        acc[1] += wv * p0.y;
        acc[2] += wv * p0.z;
        acc[3] += wv * p0.w;
        acc[4] += wv * p1.x;
        acc[5] += wv * p1.y;
        acc[6] += wv * p1.z;
        acc[7] += wv * p1.w;
    }

    // ---------- reduce across 16 cs lanes ----------
#pragma unroll
    for (int b = 0; b < BATCH; ++b) {
        float v = acc[b];
        v += __shfl_xor(v, 1);
        v += __shfl_xor(v, 2);
        v += __shfl_xor(v, 4);
        v += __shfl_xor(v, 8);
        acc[b] = v;
    }

    if (cs == 0) {
#pragma unroll
        for (int b = 0; b < BATCH; ++b)
            out[(size_t)b * (KN * P_TOTAL) + (size_t)k * P_TOTAL + p] = acc[b];
    }
}

extern "C" void kernel_launch(void* const* d_in, const int* in_sizes, int n_in,
                              void* d_out, int out_size, void* d_ws, size_t ws_size,
                              hipStream_t stream) {
    const float* x    = (const float*)d_in[0];   // [8,16,128,128] f32
    const float* wts  = (const float*)d_in[1];   // [16384,16,144] f32
    const int*   hidx = (const int*)d_in[2];     // [16384,144] int32
    float* out = (float*)d_out;                  // [8,16,16384] f32

    // Workspace intentionally untouched: avoid charging the 576 MB d_ws poison
    // fill to our timed iteration.
    (void)d_ws; (void)ws_size;

    abc2d_direct<<<P_TOTAL, 256, 0, stream>>>(x, wts, hidx, out);
}

// Round 2
// 250.316 us; speedup vs baseline: 1.4760x; 1.4760x over previous
//
#include <hip/hip_runtime.h>
#include <hip/hip_bf16.h>

// Problem constants (from reference)
#define P_TOTAL 16384      // H*W pixels
#define KN      16         // kernels per pixel
#define CK      144        // in_channel * kernel_size
#define BATCH   8
#define IMG     262144     // C*H*W
#define PSTRIDE 12         // LDS row stride in floats (48B, 16B-aligned for b128)

// ---------------- transpose+quantize: x[b][id] (f32) -> xt[id][b] (bf16) ----------------
// 4.19 MB result ~fits a 4 MB per-XCD L2 -> hash gather becomes mostly L2 hits.
// One gather index = one 16B contiguous chunk (single dwordx4, single line).
// x is read-once here -> nontemporal, don't pollute L2 ahead of the gather phase.
__global__ __launch_bounds__(256) void transpose_x_bf16(
    const float* __restrict__ x, float4* __restrict__ xt)
{
    const int i = blockIdx.x * 256 + threadIdx.x;   // id in [0, IMG)
    union { __hip_bfloat16 h[8]; float4 f4; } u;
#pragma unroll
    for (int b = 0; b < BATCH; ++b)
        u.h[b] = __float2bfloat16(
            __builtin_nontemporal_load(&x[(size_t)b * IMG + i]));  // coalesced per b
    xt[i] = u.f4;   // regular store: warm L2 with the gather table
}

// ---------------- main kernel ----------------
// Budget note (round 1 post-mortem): the ~180 us of 576 MB d_ws poison fills are
// UNCONDITIONAL harness tax (ran even with d_ws untouched). Only the ~54 us kernel
// time is ours to optimize. Changes vs round -1 baseline:
//  1) gather (hidx -> xt) issued BEFORE the weight prefetch, so the LDS write's
//     waitcnt keeps the 9 weight loads in flight across the barrier (no vmcnt(0)).
//  2) weights/hidx nontemporal-loaded, out nontemporal-stored: the 151 MB
//     read-once weight stream must not evict the 4.19 MB xt table from the 4 MB
//     per-XCD L2 (gather entries have ~9x temporal reuse: 2.36M draws / 262k ids).
__global__ __launch_bounds__(256) void abc2d_xt(
    const float4* __restrict__ xt,    // bf16x8 [IMG]
    const float*  __restrict__ w,     // [P, KN, CK]
    const int*    __restrict__ hidx,  // [P, CK]
    float* __restrict__ out)          // [B, KN, P]
{
    __shared__ float patch[CK * PSTRIDE];   // patch[c][b], f32

    // XCD swizzle: consecutive p on the same XCD -> output lines merge in L2,
    // weight stream contiguous per XCD.
    const int bid = blockIdx.x;
    const int p   = (bid & 7) * (P_TOTAL / 8) + (bid >> 3);
    const int t   = threadIdx.x;
    const int k   = t >> 4;
    const int cs  = t & 15;

    // ---------- gather issued FIRST (see note 1) ----------
    const bool do_g = (t < CK);
    float4 g;
    if (do_g) {
        const int id = __builtin_nontemporal_load(&hidx[p * CK + t]); // coalesced, read-once
        g = xt[id];                          // cached 16B load — want L2 hits
    }

    // ---------- weight prefetch: 9 x 4B/lane, 16-lane 64B runs ----------
    const float* wp = w + (size_t)p * (KN * CK) + (size_t)k * CK;
    float wreg[9];
#pragma unroll
    for (int i = 0; i < 9; ++i)
        wreg[i] = __builtin_nontemporal_load(&wp[cs + 16 * i]);   // read-once stream

    // ---------- LDS fill (waits only on the gather, weights stay in flight) ----------
    if (do_g) {
        union { __hip_bfloat16 h[8]; float4 f4; } u;
        u.f4 = g;
        float* pr = &patch[t * PSTRIDE];
        *reinterpret_cast<float4*>(pr) = make_float4(
            __bfloat162float(u.h[0]), __bfloat162float(u.h[1]),
            __bfloat162float(u.h[2]), __bfloat162float(u.h[3]));
        *reinterpret_cast<float4*>(pr + 4) = make_float4(
            __bfloat162float(u.h[4]), __bfloat162float(u.h[5]),
            __bfloat162float(u.h[6]), __bfloat162float(u.h[7]));
    }
    __syncthreads();

    // ---------- compute phase ----------
    // c = cs + 16*i: LDS word-step 12/lane, gcd(12,32)=4 -> 2-way alias = free
    // (keep the cs+16i c-partition: float4 weight loads would change it to a
    //  4cs-based partition whose LDS read pattern is an 8-way bank conflict)
    float acc[BATCH];
#pragma unroll
    for (int b = 0; b < BATCH; ++b) acc[b] = 0.f;

#pragma unroll
    for (int i = 0; i < 9; ++i) {
        const int c = cs + 16 * i;
        const float wv = wreg[i];
        const float* pr = &patch[c * PSTRIDE];
        const float4 p0 = *reinterpret_cast<const float4*>(pr);
        const float4 p1 = *reinterpret_cast<const float4*>(pr + 4);
        acc[0] += wv * p0.x;
        acc[1] += wv * p0.y;
        acc[2] += wv * p0.z;
        acc[3] += wv * p0.w;
        acc[4] += wv * p1.x;
        acc[5] += wv * p1.y;
        acc[6] += wv * p1.z;
        acc[7] += wv * p1.w;
    }

    // ---------- reduce across 16 cs lanes ----------
#pragma unroll
    for (int b = 0; b < BATCH; ++b) {
        float v = acc[b];
        v += __shfl_xor(v, 1);
        v += __shfl_xor(v, 2);
        v += __shfl_xor(v, 4);
        v += __shfl_xor(v, 8);
        acc[b] = v;
    }

    if (cs == 0) {
#pragma unroll
        for (int b = 0; b < BATCH; ++b)
            __builtin_nontemporal_store(
                acc[b], &out[(size_t)b * (KN * P_TOTAL) + (size_t)k * P_TOTAL + p]);
    }
}

// ---------------- fallback: direct f32 gather (no workspace) ----------------
__global__ __launch_bounds__(256) void abc2d_direct(
    const float* __restrict__ x, const float* __restrict__ w,
    const int* __restrict__ hidx, float* __restrict__ out)
{
    __shared__ float patch[CK * PSTRIDE];
    const int bid = blockIdx.x;
    const int p   = (bid & 7) * (P_TOTAL / 8) + (bid >> 3);
    const int t   = threadIdx.x;
    const int k   = t >> 4;
    const int cs  = t & 15;

    if (t < CK) {
        const int id = hidx[p * CK + t];
        float v[BATCH];
#pragma unroll
        for (int b = 0; b < BATCH; ++b) v[b] = x[(size_t)b * IMG + (size_t)id];
        float* pr = &patch[t * PSTRIDE];
        *reinterpret_cast<float4*>(pr)     = make_float4(v[0], v[1], v[2], v[3]);
        *reinterpret_cast<float4*>(pr + 4) = make_float4(v[4], v[5], v[6], v[7]);
    }

    const float* wp = w + (size_t)p * (KN * CK) + (size_t)k * CK;
    float wreg[9];
#pragma unroll
    for (int i = 0; i < 9; ++i) wreg[i] = wp[cs + 16 * i];
    __syncthreads();

    float acc[BATCH];
#pragma unroll
    for (int b = 0; b < BATCH; ++b) acc[b] = 0.f;
#pragma unroll
    for (int i = 0; i < 9; ++i) {
        const float wv = wreg[i];
        const float* pr = &patch[(cs + 16 * i) * PSTRIDE];
        const float4 p0 = *reinterpret_cast<const float4*>(pr);
        const float4 p1 = *reinterpret_cast<const float4*>(pr + 4);
        acc[0] += wv * p0.x; acc[1] += wv * p0.y; acc[2] += wv * p0.z; acc[3] += wv * p0.w;
        acc[4] += wv * p1.x; acc[5] += wv * p1.y; acc[6] += wv * p1.z; acc[7] += wv * p1.w;
    }
#pragma unroll
    for (int b = 0; b < BATCH; ++b) {
        float v = acc[b];
        v += __shfl_xor(v, 1); v += __shfl_xor(v, 2);
        v += __shfl_xor(v, 4); v += __shfl_xor(v, 8);
        acc[b] = v;
    }
    if (cs == 0) {
#pragma unroll
        for (int b = 0; b < BATCH; ++b)
            out[(size_t)b * (KN * P_TOTAL) + (size_t)k * P_TOTAL + p] = acc[b];
    }
}

extern "C" void kernel_launch(void* const* d_in, const int* in_sizes, int n_in,
                              void* d_out, int out_size, void* d_ws, size_t ws_size,
                              hipStream_t stream) {
    const float* x    = (const float*)d_in[0];   // [8,16,128,128] f32
    const float* wts  = (const float*)d_in[1];   // [16384,16,144] f32
    const int*   hidx = (const int*)d_in[2];     // [16384,144] int32
    float* out = (float*)d_out;                  // [8,16,16384] f32

    const size_t xt_bytes = (size_t)IMG * BATCH * sizeof(__hip_bfloat16);  // 4.19 MB
    if (ws_size >= xt_bytes) {
        float4* xt = (float4*)d_ws;
        transpose_x_bf16<<<IMG / 256, 256, 0, stream>>>(x, xt);
        abc2d_xt<<<P_TOTAL, 256, 0, stream>>>(xt, wts, hidx, out);
    } else {
        abc2d_direct<<<P_TOTAL, 256, 0, stream>>>(x, wts, hidx, out);
    }
}

// Round 3
// 239.833 us; speedup vs baseline: 1.5405x; 1.0437x over previous
//
#include <hip/hip_runtime.h>
#include <hip/hip_bf16.h>

// Problem constants (from reference)
#define P_TOTAL 16384      // H*W pixels
#define KN      16         // kernels per pixel
#define CK      144        // in_channel * kernel_size
#define BATCH   8
#define IMG     262144     // C*H*W
#define PSTRIDE 12         // LDS row stride in floats (48B, 16B-aligned for b128)

// Session budget note: ~176 us of the reported dur_us is an unconditional harness
// tax (2x 576 MB d_ws poison fills at ~88 us). Kernel-side budget is ~59 us at
// baseline; floor ~34 us (170 MB mandatory traffic @ 6.3 TB/s + overhead).
//
// Round 2 post-mortem: nt-store on out regressed (+15 us) — out depends on L2
// write-combining across consecutive-p blocks; evict-first flushes partial lines.
// REVERTED. This round tests ONE mechanism: nt-load on the read-once streams
// (x during transpose, weights in main) so they don't evict the 4.19 MB xt
// gather table from the 4 MB per-XCD L2 (xt entries have ~9x temporal reuse).

// ---------------- transpose+quantize: x[b][id] (f32) -> xt[id][b] (bf16) ----------------
__global__ __launch_bounds__(256) void transpose_x_bf16(
    const float* __restrict__ x, float4* __restrict__ xt)
{
    const int i = blockIdx.x * 256 + threadIdx.x;   // id in [0, IMG)
    union { __hip_bfloat16 h[8]; float4 f4; } u;
#pragma unroll
    for (int b = 0; b < BATCH; ++b)
        u.h[b] = __float2bfloat16(
            __builtin_nontemporal_load(&x[(size_t)b * IMG + i]));  // read-once stream
    xt[i] = u.f4;   // regular store: warm L2 with the gather table
}

// ---------------- main kernel (round -1 structure, + nt weight loads) ----------------
__global__ __launch_bounds__(256) void abc2d_xt(
    const float4* __restrict__ xt,    // bf16x8 [IMG]
    const float*  __restrict__ w,     // [P, KN, CK]
    const int*    __restrict__ hidx,  // [P, CK]
    float* __restrict__ out)          // [B, KN, P]
{
    __shared__ float patch[CK * PSTRIDE];   // patch[c][b], f32

    // XCD swizzle: consecutive p on the same XCD -> output lines merge in L2
    const int bid = blockIdx.x;
    const int p   = (bid & 7) * (P_TOTAL / 8) + (bid >> 3);
    const int t   = threadIdx.x;
    const int k   = t >> 4;
    const int cs  = t & 15;

    // ---- weight prefetch first (baseline order): the 9-load stream drains
    // while we wait on the hidx->xt dependent chain, so its latency is free ----
    const float* wp = w + (size_t)p * (KN * CK) + (size_t)k * CK;
    float wreg[9];
#pragma unroll
    for (int i = 0; i < 9; ++i)
        wreg[i] = __builtin_nontemporal_load(&wp[cs + 16 * i]);  // read-once stream

    // ---------- gather phase ----------
    if (t < CK) {
        const int id = hidx[p * CK + t];          // regular load (coalesced)
        union { __hip_bfloat16 h[8]; float4 f4; } u;
        u.f4 = xt[id];                            // cached 16B load — want L2 hits
        float* pr = &patch[t * PSTRIDE];
        *reinterpret_cast<float4*>(pr) = make_float4(
            __bfloat162float(u.h[0]), __bfloat162float(u.h[1]),
            __bfloat162float(u.h[2]), __bfloat162float(u.h[3]));
        *reinterpret_cast<float4*>(pr + 4) = make_float4(
            __bfloat162float(u.h[4]), __bfloat162float(u.h[5]),
            __bfloat162float(u.h[6]), __bfloat162float(u.h[7]));
    }
    __syncthreads();

    // ---------- compute phase ----------
    // c = cs + 16*i: LDS word-step 12/lane, gcd(12,32)=4 -> 2-way alias = free
    float acc[BATCH];
#pragma unroll
    for (int b = 0; b < BATCH; ++b) acc[b] = 0.f;

#pragma unroll
    for (int i = 0; i < 9; ++i) {
        const int c = cs + 16 * i;
        const float wv = wreg[i];
        const float* pr = &patch[c * PSTRIDE];
        const float4 p0 = *reinterpret_cast<const float4*>(pr);
        const float4 p1 = *reinterpret_cast<const float4*>(pr + 4);
        acc[0] += wv * p0.x;
        acc[1] += wv * p0.y;
        acc[2] += wv * p0.z;
        acc[3] += wv * p0.w;
        acc[4] += wv * p1.x;
        acc[5] += wv * p1.y;
        acc[6] += wv * p1.z;
        acc[7] += wv * p1.w;
    }

    // ---------- reduce across 16 cs lanes ----------
#pragma unroll
    for (int b = 0; b < BATCH; ++b) {
        float v = acc[b];
        v += __shfl_xor(v, 1);
        v += __shfl_xor(v, 2);
        v += __shfl_xor(v, 4);
        v += __shfl_xor(v, 8);
        acc[b] = v;
    }

    if (cs == 0) {
#pragma unroll
        for (int b = 0; b < BATCH; ++b)
            out[(size_t)b * (KN * P_TOTAL) + (size_t)k * P_TOTAL + p] = acc[b];  // regular store: L2 write-combine
    }
}

// ---------------- fallback: direct f32 gather (no workspace) ----------------
__global__ __launch_bounds__(256) void abc2d_direct(
    const float* __restrict__ x, const float* __restrict__ w,
    const int* __restrict__ hidx, float* __restrict__ out)
{
    __shared__ float patch[CK * PSTRIDE];
    const int bid = blockIdx.x;
    const int p   = (bid & 7) * (P_TOTAL / 8) + (bid >> 3);
    const int t   = threadIdx.x;
    const int k   = t >> 4;
    const int cs  = t & 15;

    if (t < CK) {
        const int id = hidx[p * CK + t];
        float v[BATCH];
#pragma unroll
        for (int b = 0; b < BATCH; ++b) v[b] = x[(size_t)b * IMG + (size_t)id];
        float* pr = &patch[t * PSTRIDE];
        *reinterpret_cast<float4*>(pr)     = make_float4(v[0], v[1], v[2], v[3]);
        *reinterpret_cast<float4*>(pr + 4) = make_float4(v[4], v[5], v[6], v[7]);
    }

    const float* wp = w + (size_t)p * (KN * CK) + (size_t)k * CK;
    float wreg[9];
#pragma unroll
    for (int i = 0; i < 9; ++i) wreg[i] = wp[cs + 16 * i];
    __syncthreads();

    float acc[BATCH];
#pragma unroll
    for (int b = 0; b < BATCH; ++b) acc[b] = 0.f;
#pragma unroll
    for (int i = 0; i < 9; ++i) {
        const float wv = wreg[i];
        const float* pr = &patch[(cs + 16 * i) * PSTRIDE];
        const float4 p0 = *reinterpret_cast<const float4*>(pr);
        const float4 p1 = *reinterpret_cast<const float4*>(pr + 4);
        acc[0] += wv * p0.x; acc[1] += wv * p0.y; acc[2] += wv * p0.z; acc[3] += wv * p0.w;
        acc[4] += wv * p1.x; acc[5] += wv * p1.y; acc[6] += wv * p1.z; acc[7] += wv * p1.w;
    }
#pragma unroll
    for (int b = 0; b < BATCH; ++b) {
        float v = acc[b];
        v += __shfl_xor(v, 1); v += __shfl_xor(v, 2);
        v += __shfl_xor(v, 4); v += __shfl_xor(v, 8);
        acc[b] = v;
    }
    if (cs == 0) {
#pragma unroll
        for (int b = 0; b < BATCH; ++b)
            out[(size_t)b * (KN * P_TOTAL) + (size_t)k * P_TOTAL + p] = acc[b];
    }
}

extern "C" void kernel_launch(void* const* d_in, const int* in_sizes, int n_in,
                              void* d_out, int out_size, void* d_ws, size_t ws_size,
                              hipStream_t stream) {
    const float* x    = (const float*)d_in[0];   // [8,16,128,128] f32
    const float* wts  = (const float*)d_in[1];   // [16384,16,144] f32
    const int*   hidx = (const int*)d_in[2];     // [16384,144] int32
    float* out = (float*)d_out;                  // [8,16,16384] f32

    const size_t xt_bytes = (size_t)IMG * BATCH * sizeof(__hip_bfloat16);  // 4.19 MB
    if (ws_size >= xt_bytes) {
        float4* xt = (float4*)d_ws;
        transpose_x_bf16<<<IMG / 256, 256, 0, stream>>>(x, xt);
        abc2d_xt<<<P_TOTAL, 256, 0, stream>>>(xt, wts, hidx, out);
    } else {
        abc2d_direct<<<P_TOTAL, 256, 0, stream>>>(x, wts, hidx, out);
    }
}

// Round 4
// 235.356 us; speedup vs baseline: 1.5698x; 1.0190x over previous
//
#include <hip/hip_runtime.h>
#include <hip/hip_bf16.h>

// Problem constants (from reference)
#define P_TOTAL 16384      // H*W pixels
#define KN      16         // kernels per pixel
#define CK      144        // in_channel * kernel_size
#define BATCH   8
#define IMG     262144     // C*H*W
#define PSTRIDE 12         // LDS row stride in floats (48B, 16B-aligned for b128)
#define NP      8          // pixels per block (software pipeline depth)
#define NCHUNK  (P_TOTAL / NP)   // 2048 blocks

// Session budget: ~176 us of dur_us is unconditional harness tax (2x 576 MB d_ws
// poison fills @ ~88 us). Kernel-side budget ~61 us at baseline; floor ~30 us.
// R3 post-mortem: nt-load on read-once streams = NEUTRAL -> L2-thrash theory dead.
// R4 theory: per-block one-shot {10 loads -> 2-deep dependent gather -> barrier ->
// tiny compute -> exit} is latency-bound (VALUBusy 8%, BW 49%, occupancy 83%).
// Fix: 8 pixels per block, double-buffered LDS, 3-deep issue pipeline with counted
// vmcnt (weights for p+1 in flight across every wait), coalesced staged out-flush.

// ---------------- transpose+quantize: x[b][id] (f32) -> xt[id][b] (bf16) ----------------
__global__ __launch_bounds__(256) void transpose_x_bf16(
    const float* __restrict__ x, float4* __restrict__ xt)
{
    const int i = blockIdx.x * 256 + threadIdx.x;   // id in [0, IMG)
    union { __hip_bfloat16 h[8]; float4 f4; } u;
#pragma unroll
    for (int b = 0; b < BATCH; ++b)
        u.h[b] = __float2bfloat16(
            __builtin_nontemporal_load(&x[(size_t)b * IMG + i]));  // read-once stream
    xt[i] = u.f4;   // regular store: warm caches with the gather table
}

// ---------------- main kernel: 8-pixel software-pipelined block ----------------
__global__ __launch_bounds__(256) void abc2d_xt_pipe(
    const float4* __restrict__ xt,    // bf16x8 [IMG]
    const float*  __restrict__ w,     // [P, KN, CK]
    const int*    __restrict__ hidx,  // [P, CK]
    float* __restrict__ out)          // [B, KN, P]
{
    __shared__ float patch[2][CK * PSTRIDE];        // 2 x 6912 B double buffer
    __shared__ float outbuf[KN * BATCH * NP];       // 4 kB staged output

    // XCD swizzle over 2048 chunks (2048 % 8 == 0 -> bijective)
    const int bid   = blockIdx.x;
    const int chunk = (bid & 7) * (NCHUNK / 8) + (bid >> 3);
    const int p0    = chunk * NP;                    // 8 consecutive pixels
    const int t     = threadIdx.x;
    const int k     = t >> 4;
    const int cs    = t & 15;
    const bool do_g = (t < CK);

    float wcur[9], wnxt[9];
    float4 g;                 // gather value for the current pixel (in flight)
    int id_nxt = 0;           // hash index for the NEXT pixel (in flight)

    // ---------------- prologue ----------------
    {
        const float* wp = w + (size_t)p0 * (KN * CK) + (size_t)k * CK + cs;
#pragma unroll
        for (int i = 0; i < 9; ++i)
            wcur[i] = __builtin_nontemporal_load(wp + 16 * i);   // w_0 in flight
    }
    if (do_g) {
        const int id0 = hidx[p0 * CK + t];       // wait (drains w_0 too; prologue only)
        g = xt[id0];                              // issue g_0
        id_nxt = hidx[(p0 + 1) * CK + t];         // issue id_1
    }

    // ---------------- steady-state pipeline ----------------
#pragma unroll
    for (int j = 0; j < NP; ++j) {
        const int jb = j & 1;

        // issue next-pixel weight stream FIRST (independent, stays in flight
        // across the g-wait, the barrier, and the id-wait below)
        if (j + 1 < NP) {
            const float* wp = w + (size_t)(p0 + j + 1) * (KN * CK) + (size_t)k * CK + cs;
#pragma unroll
            for (int i = 0; i < 9; ++i)
                wnxt[i] = __builtin_nontemporal_load(wp + 16 * i);
        }

        // LDS fill for pixel j (waits only g_j: counted vmcnt, w_{j+1}+id stay out)
        if (do_g) {
            union { __hip_bfloat16 h[8]; float4 f4; } u;
            u.f4 = g;
            float* pr = &patch[jb][t * PSTRIDE];
            *reinterpret_cast<float4*>(pr) = make_float4(
                __bfloat162float(u.h[0]), __bfloat162float(u.h[1]),
                __bfloat162float(u.h[2]), __bfloat162float(u.h[3]));
            *reinterpret_cast<float4*>(pr + 4) = make_float4(
                __bfloat162float(u.h[4]), __bfloat162float(u.h[5]),
                __bfloat162float(u.h[6]), __bfloat162float(u.h[7]));
        }
        __syncthreads();

        // issue next gather chain (wait id_{j+1} = counted vmcnt(9): weights in flight)
        if (do_g && j + 1 < NP) {
            g = xt[id_nxt];                                   // issue g_{j+1}
            if (j + 2 < NP) id_nxt = hidx[(p0 + j + 2) * CK + t];  // issue id_{j+2}
        }

        // ---------- compute pixel j (overlaps all in-flight loads) ----------
        float acc[BATCH];
#pragma unroll
        for (int b = 0; b < BATCH; ++b) acc[b] = 0.f;

#pragma unroll
        for (int i = 0; i < 9; ++i) {
            const int c = cs + 16 * i;                 // word-step 12/lane: 2-way = free
            const float wv = wcur[i];
            const float* pr = &patch[jb][c * PSTRIDE];
            const float4 q0 = *reinterpret_cast<const float4*>(pr);
            const float4 q1 = *reinterpret_cast<const float4*>(pr + 4);
            acc[0] += wv * q0.x;
            acc[1] += wv * q0.y;
            acc[2] += wv * q0.z;
            acc[3] += wv * q0.w;
            acc[4] += wv * q1.x;
            acc[5] += wv * q1.y;
            acc[6] += wv * q1.z;
            acc[7] += wv * q1.w;
        }

        // reduce across the 16 cs lanes
#pragma unroll
        for (int b = 0; b < BATCH; ++b) {
            float v = acc[b];
            v += __shfl_xor(v, 1);
            v += __shfl_xor(v, 2);
            v += __shfl_xor(v, 4);
            v += __shfl_xor(v, 8);
            acc[b] = v;
        }

        // stage into LDS (scattered 4B global stores eliminated)
        if (cs == 0) {
#pragma unroll
            for (int b = 0; b < BATCH; ++b)
                outbuf[(k * BATCH + b) * NP + j] = acc[b];
        }

        // rotate weight registers (full unroll -> SSA rename, no v_movs)
        if (j + 1 < NP) {
#pragma unroll
            for (int i = 0; i < 9; ++i) wcur[i] = wnxt[i];
        }
    }

    // ---------------- coalesced output flush: 32B per (b,k) row ----------------
    __syncthreads();
    if (t < KN * BATCH) {
        const int kk = t >> 3;
        const int bb = t & 7;
        const float* src = &outbuf[(kk * BATCH + bb) * NP];
        const float4 v0 = *reinterpret_cast<const float4*>(src);
        const float4 v1 = *reinterpret_cast<const float4*>(src + 4);
        float* dst = &out[((size_t)bb * KN + kk) * P_TOTAL + p0];   // p0 8-aligned -> 32B aligned
        *reinterpret_cast<float4*>(dst)     = v0;
        *reinterpret_cast<float4*>(dst + 4) = v1;
    }
}

// ---------------- fallback: direct f32 gather (no workspace) ----------------
__global__ __launch_bounds__(256) void abc2d_direct(
    const float* __restrict__ x, const float* __restrict__ w,
    const int* __restrict__ hidx, float* __restrict__ out)
{
    __shared__ float patch[CK * PSTRIDE];
    const int bid = blockIdx.x;
    const int p   = (bid & 7) * (P_TOTAL / 8) + (bid >> 3);
    const int t   = threadIdx.x;
    const int k   = t >> 4;
    const int cs  = t & 15;

    if (t < CK) {
        const int id = hidx[p * CK + t];
        float v[BATCH];
#pragma unroll
        for (int b = 0; b < BATCH; ++b) v[b] = x[(size_t)b * IMG + (size_t)id];
        float* pr = &patch[t * PSTRIDE];
        *reinterpret_cast<float4*>(pr)     = make_float4(v[0], v[1], v[2], v[3]);
        *reinterpret_cast<float4*>(pr + 4) = make_float4(v[4], v[5], v[6], v[7]);
    }

    const float* wp = w + (size_t)p * (KN * CK) + (size_t)k * CK;
    float wreg[9];
#pragma unroll
    for (int i = 0; i < 9; ++i) wreg[i] = wp[cs + 16 * i];
    __syncthreads();

    float acc[BATCH];
#pragma unroll
    for (int b = 0; b < BATCH; ++b) acc[b] = 0.f;
#pragma unroll
    for (int i = 0; i < 9; ++i) {
        const float wv = wreg[i];
        const float* pr = &patch[(cs + 16 * i) * PSTRIDE];
        const float4 q0 = *reinterpret_cast<const float4*>(pr);
        const float4 q1 = *reinterpret_cast<const float4*>(pr + 4);
        acc[0] += wv * q0.x; acc[1] += wv * q0.y; acc[2] += wv * q0.z; acc[3] += wv * q0.w;
        acc[4] += wv * q1.x; acc[5] += wv * q1.y; acc[6] += wv * q1.z; acc[7] += wv * q1.w;
    }
#pragma unroll
    for (int b = 0; b < BATCH; ++b) {
        float v = acc[b];
        v += __shfl_xor(v, 1); v += __shfl_xor(v, 2);
        v += __shfl_xor(v, 4); v += __shfl_xor(v, 8);
        acc[b] = v;
    }
    if (cs == 0) {
#pragma unroll
        for (int b = 0; b < BATCH; ++b)
            out[(size_t)b * (KN * P_TOTAL) + (size_t)k * P_TOTAL + p] = acc[b];
    }
}

extern "C" void kernel_launch(void* const* d_in, const int* in_sizes, int n_in,
                              void* d_out, int out_size, void* d_ws, size_t ws_size,
                              hipStream_t stream) {
    const float* x    = (const float*)d_in[0];   // [8,16,128,128] f32
    const float* wts  = (const float*)d_in[1];   // [16384,16,144] f32
    const int*   hidx = (const int*)d_in[2];     // [16384,144] int32
    float* out = (float*)d_out;                  // [8,16,16384] f32

    const size_t xt_bytes = (size_t)IMG * BATCH * sizeof(__hip_bfloat16);  // 4.19 MB
    if (ws_size >= xt_bytes) {
        float4* xt = (float4*)d_ws;
        transpose_x_bf16<<<IMG / 256, 256, 0, stream>>>(x, xt);
        abc2d_xt_pipe<<<NCHUNK, 256, 0, stream>>>(xt, wts, hidx, out);
    } else {
        abc2d_direct<<<P_TOTAL, 256, 0, stream>>>(x, wts, hidx, out);
    }
}